// Round 2
// baseline (247.259 us; speedup 1.0000x reference)
//
#include <hip/hip_runtime.h>

// DynamicRouting: grouped 1x1 conv (einsum bgihw,gfi->bgfhw) + 3-iter routing.
// B=16, G=8, FI=FO=64, HW=4096. Fully fused: con never touches HBM.
//
// R2: fp16 (not bf16) for x; w split into wh+wl fp16 pair (error ~2^-22 on w,
// ~2^-12 on x) -> con relative error ~1.5e-4, 25x better than R1's bf16.
// Structure unchanged: stage 512ch x 64px x-tile to LDS transposed [g][p][i];
// each wave computes con[8g][64f][16px] via 16x16x32 f16 MFMA (4 per (g,t):
// x*wh + x*wl over two K=32 halves); routing closes f-sums with per-lane FMAs
// + shfl_xor(16/32) butterflies.

typedef __attribute__((ext_vector_type(8))) _Float16 half8;
typedef __attribute__((ext_vector_type(4))) float f32x4;

#define NG   8
#define NFI  64
#define NFO  64
#define HW   4096
#define PT   64     // pixel tile per workgroup
#define XPAD 72     // padded i-stride in xs (16B-aligned rows: 144 B)

__device__ __forceinline__ float sigmoidf_fast(float v) {
    // exp2-based sigmoid; saturates correctly for |v| large (1/inf -> 0)
    float e = __builtin_amdgcn_exp2f(-1.44269504088896f * v);
    return __builtin_amdgcn_rcpf(1.0f + e);
}

// ---- kernel 1: split weights fp32 -> (wh, wl) fp16 into d_ws ----
__global__ __launch_bounds__(256)
void wconv_kernel(const float* __restrict__ w, _Float16* __restrict__ wh,
                  _Float16* __restrict__ wl) {
    int idx = (blockIdx.x * 256 + threadIdx.x) * 4;
    f32x4 v = *(const f32x4*)(w + idx);
    _Float16 h[4], l[4];
    #pragma unroll
    for (int k = 0; k < 4; ++k) {
        h[k] = (_Float16)v[k];
        l[k] = (_Float16)(v[k] - (float)h[k]);
    }
    *(ulong1*)(wh + idx) = *(ulong1*)h;   // 8B store
    *(ulong1*)(wl + idx) = *(ulong1*)l;
}

// ---- kernel 2: fused conv + routing ----
__global__ __launch_bounds__(256, 2)
void routing_kernel(const float* __restrict__ x,
                    const _Float16* __restrict__ wh,
                    const _Float16* __restrict__ wl,
                    const float* __restrict__ bias,
                    float* __restrict__ out) {
    // fp16 x-tile, transposed: xs[(g*PT + p)*XPAD + i]   (73728 B -> 2 WG/CU)
    __shared__ __align__(16) _Float16 xs[NG * PT * XPAD];

    const int tid = threadIdx.x;
    const int b   = blockIdx.x >> 6;          // batch
    const int p0  = (blockIdx.x & 63) << 6;   // pixel tile base within b

    const float* xb = x + (size_t)b * (NG * NFI) * HW + p0;

    // ---- stage: 512 rows x 64 px, coalesced dwordx4, transpose into LDS ----
    #pragma unroll 8
    for (int j = 0; j < 32; ++j) {
        int flat = j * 256 + tid;            // 0..8191 chunk id
        int row  = flat >> 4;                // channel 0..511 (= g*64 + i)
        int pc   = (flat & 15) << 2;         // pixel 0..60
        f32x4 v = *(const f32x4*)(xb + (size_t)row * HW + pc);
        int g = row >> 6, i = row & 63;
        _Float16* basep = xs + (g * PT) * XPAD + i;
        basep[(pc + 0) * XPAD] = (_Float16)v[0];
        basep[(pc + 1) * XPAD] = (_Float16)v[1];
        basep[(pc + 2) * XPAD] = (_Float16)v[2];
        basep[(pc + 3) * XPAD] = (_Float16)v[3];
    }
    __syncthreads();

    const int lane = tid & 63;
    const int wv   = tid >> 6;      // wave 0..3 -> 16-px slice
    const int pl   = lane & 15;     // MFMA col / A-m / B-n lane index
    const int q    = lane >> 4;     // quad: k-octet select, C row group
    const int pw   = wv * 16 + pl;  // pixel within tile

    // con[g][f][p]: f = t*16 + q*4 + r, p = p0 + pw
    f32x4 acc[NG][4];
    #pragma unroll
    for (int g = 0; g < NG; ++g)
        #pragma unroll
        for (int t = 0; t < 4; ++t)
            acc[g][t] = (f32x4){0.f, 0.f, 0.f, 0.f};

    #pragma unroll
    for (int g = 0; g < NG; ++g) {
        const _Float16* xrow = xs + (g * PT + pw) * XPAD;
        half8 b0 = *(const half8*)(xrow + q * 8);        // k = q*8..q*8+7
        half8 b1 = *(const half8*)(xrow + 32 + q * 8);   // k = 32+q*8..
        const int wgoff = g * (NFO * NFI);
        #pragma unroll
        for (int t = 0; t < 4; ++t) {
            const int roff = wgoff + (t * 16 + pl) * NFI + q * 8;
            half8 a0h = *(const half8*)(wh + roff);
            half8 a1h = *(const half8*)(wh + roff + 32);
            half8 a0l = *(const half8*)(wl + roff);
            half8 a1l = *(const half8*)(wl + roff + 32);
            acc[g][t] = __builtin_amdgcn_mfma_f32_16x16x32_f16(a0h, b0, acc[g][t], 0, 0, 0);
            acc[g][t] = __builtin_amdgcn_mfma_f32_16x16x32_f16(a1h, b1, acc[g][t], 0, 0, 0);
            acc[g][t] = __builtin_amdgcn_mfma_f32_16x16x32_f16(a0l, b0, acc[g][t], 0, 0, 0);
            acc[g][t] = __builtin_amdgcn_mfma_f32_16x16x32_f16(a1l, b1, acc[g][t], 0, 0, 0);
        }
    }

    // ---- routing (all fp32, per pixel) ----
    // iter 0: v0[f] = 0.5*sum_g con ; beta1[g] = sum_f v0*con
    float v0[4][4];
    #pragma unroll
    for (int t = 0; t < 4; ++t)
        #pragma unroll
        for (int r = 0; r < 4; ++r) {
            float s = 0.f;
            #pragma unroll
            for (int g = 0; g < NG; ++g) s += acc[g][t][r];
            v0[t][r] = 0.5f * s;
        }

    float beta[NG], alpha[NG];
    #pragma unroll
    for (int g = 0; g < NG; ++g) {
        float s = 0.f;
        #pragma unroll
        for (int t = 0; t < 4; ++t)
            #pragma unroll
            for (int r = 0; r < 4; ++r)
                s += v0[t][r] * acc[g][t][r];
        s += __shfl_xor(s, 16);   // close f-sum across the 4 q-lanes
        s += __shfl_xor(s, 32);
        beta[g]  = s;
        alpha[g] = sigmoidf_fast(s);
    }

    // iter 1: v1[f] = sum_g alpha*con ; beta2 = beta1 + sum_f v1*con
    #pragma unroll
    for (int t = 0; t < 4; ++t)
        #pragma unroll
        for (int r = 0; r < 4; ++r) {
            float s = 0.f;
            #pragma unroll
            for (int g = 0; g < NG; ++g) s += alpha[g] * acc[g][t][r];
            v0[t][r] = s;  // reuse as v1
        }
    #pragma unroll
    for (int g = 0; g < NG; ++g) {
        float s = 0.f;
        #pragma unroll
        for (int t = 0; t < 4; ++t)
            #pragma unroll
            for (int r = 0; r < 4; ++r)
                s += v0[t][r] * acc[g][t][r];
        s += __shfl_xor(s, 16);
        s += __shfl_xor(s, 32);
        beta[g] += s;
        alpha[g] = sigmoidf_fast(beta[g]);
    }

    // iter 2: out[f] = sum_g alpha2*con + bias[f]
    #pragma unroll
    for (int t = 0; t < 4; ++t)
        #pragma unroll
        for (int r = 0; r < 4; ++r) {
            int f = t * 16 + q * 4 + r;
            float s = bias[f];
            #pragma unroll
            for (int g = 0; g < NG; ++g) s += alpha[g] * acc[g][t][r];
            out[((size_t)(b * NFO + f)) * HW + p0 + pw] = s;
        }
}

extern "C" void kernel_launch(void* const* d_in, const int* in_sizes, int n_in,
                              void* d_out, int out_size, void* d_ws, size_t ws_size,
                              hipStream_t stream) {
    const float* x    = (const float*)d_in[0];
    const float* w    = (const float*)d_in[1];
    const float* bias = (const float*)d_in[2];
    float* out = (float*)d_out;
    _Float16* wh = (_Float16*)d_ws;            // 65536 B
    _Float16* wl = wh + NG * NFO * NFI;        // 65536 B (total 128 KiB scratch)

    // re-split w every launch (d_ws is re-poisoned before each timed call)
    wconv_kernel<<<32, 256, 0, stream>>>(w, wh, wl);
    routing_kernel<<<1024, 256, 0, stream>>>(x, wh, wl, bias, out);
}

// Round 3
// 215.462 us; speedup vs baseline: 1.1476x; 1.1476x over previous
//
#include <hip/hip_runtime.h>

// DynamicRouting: grouped 1x1 conv (einsum bgihw,gfi->bgfhw) + 3-iter routing.
// B=16, G=8, FI=FO=64, HW=4096. Fully fused: con never touches HBM.
//
// R3: NO LDS. B-fragments (x) load directly from global: lane (pl,q) reads
// x[ch=g*64+q*8+j][px=p0+wv*16+pl] -> per instr 4x64B useful segments, every
// byte consumed exactly once. x double-buffered across g (prefetch g+1 during
// g's MFMAs). Weights pre-repacked into fragment order by wconv_kernel so each
// A-fragment is ONE contiguous coalesced dwordx4 wave-load (L1/L2-resident).
// Numerics as R2 (passed, absmax 0.125): fp16 x, w split h+l fp16, fp32 acc.

typedef __attribute__((ext_vector_type(8))) _Float16 half8;
typedef __attribute__((ext_vector_type(4))) float f32x4;

#define NG   8
#define NFI  64
#define NFO  64
#define HW   4096

__device__ __forceinline__ float sigmoidf_fast(float v) {
    float e = __builtin_amdgcn_exp2f(-1.44269504088896f * v);
    return __builtin_amdgcn_rcpf(1.0f + e);
}

// ---- kernel 1: repack weights fp32 -> fragment-ordered (h,l) fp16 ----
// wbuf[((g*4+t)*4+c)*512 + lane*8 + j]:
//   c=0: h, k=q*8+j   c=1: h, k=32+q*8+j   c=2: l, k=q*8+j   c=3: l, k=32+q*8+j
//   lane=(q<<4)|pl maps to w row (t*16+pl), so routing's A-frag load is
//   one contiguous dwordx4 per wave at offset lane*16B.
__global__ __launch_bounds__(256)
void wconv_kernel(const float* __restrict__ w, _Float16* __restrict__ wbuf) {
    int V = blockIdx.x * 256 + threadIdx.x;   // 0..8191 fragments
    int g    = V >> 10;
    int t    = (V >> 8) & 3;
    int c    = (V >> 6) & 3;                  // wave-uniform (V>>6 spans 64)
    int lane = V & 63;
    int pl = lane & 15, q = lane >> 4;
    const float* src = w + g * (NFO * NFI) + (t * 16 + pl) * NFI + (c & 1) * 32 + q * 8;
    half8 o;
    #pragma unroll
    for (int j = 0; j < 8; ++j) {
        float f = src[j];
        _Float16 h = (_Float16)f;
        o[j] = (c >> 1) ? (_Float16)(f - (float)h) : h;
    }
    *(half8*)(wbuf + (size_t)V * 8) = o;
}

// ---- kernel 2: fused conv + routing, LDS-free ----
__global__ __launch_bounds__(256, 2)
void routing_kernel(const float* __restrict__ x,
                    const _Float16* __restrict__ wbuf,
                    const float* __restrict__ bias,
                    float* __restrict__ out) {
    const int tid  = threadIdx.x;
    const int b    = blockIdx.x >> 6;          // batch
    const int p0   = (blockIdx.x & 63) << 6;   // pixel tile base
    const int lane = tid & 63;
    const int wv   = tid >> 6;                 // wave -> 16-px slice
    const int pl   = lane & 15;                // MFMA n-lane (pixel)
    const int q    = lane >> 4;                // k-octet select / C row group
    const int pw   = wv * 16 + pl;             // pixel within tile

    // lane's x column base: x[b, ch=0, p0+pw]
    const float* xg = x + (size_t)b * (NG * NFI) * HW + p0 + pw;

    f32x4 acc[NG][4];
    #pragma unroll
    for (int g = 0; g < NG; ++g)
        #pragma unroll
        for (int t = 0; t < 4; ++t)
            acc[g][t] = (f32x4){0.f, 0.f, 0.f, 0.f};

    // 16 scalar dword loads per group: ch = g*64 + {q*8+j, 32+q*8+j}
    float xv0[16], xv1[16];
    #define LOADX(G, V)                                                  \
        {                                                                \
            const float* p_ = xg + (size_t)((G) * 64 + q * 8) * HW;      \
            _Pragma("unroll")                                            \
            for (int j = 0; j < 8; ++j) {                                \
                (V)[j]     = p_[(size_t)j * HW];                         \
                (V)[8 + j] = p_[(size_t)(32 + j) * HW];                  \
            }                                                            \
        }

    LOADX(0, xv0);

    #pragma unroll
    for (int g = 0; g < NG; ++g) {
        float* cur = (g & 1) ? xv1 : xv0;
        float* nxt = (g & 1) ? xv0 : xv1;
        if (g < NG - 1) LOADX(g + 1, nxt);

        half8 b0, b1;
        #pragma unroll
        for (int j = 0; j < 8; ++j) {
            b0[j] = (_Float16)cur[j];
            b1[j] = (_Float16)cur[8 + j];
        }

        const _Float16* wg = wbuf + ((size_t)g * 4) * 4 * 512 + lane * 8;
        #pragma unroll
        for (int t = 0; t < 4; ++t) {
            const _Float16* wp = wg + (size_t)t * 4 * 512;
            half8 a0h = *(const half8*)(wp);
            half8 a1h = *(const half8*)(wp + 512);
            half8 a0l = *(const half8*)(wp + 1024);
            half8 a1l = *(const half8*)(wp + 1536);
            acc[g][t] = __builtin_amdgcn_mfma_f32_16x16x32_f16(a0h, b0, acc[g][t], 0, 0, 0);
            acc[g][t] = __builtin_amdgcn_mfma_f32_16x16x32_f16(a1h, b1, acc[g][t], 0, 0, 0);
            acc[g][t] = __builtin_amdgcn_mfma_f32_16x16x32_f16(a0l, b0, acc[g][t], 0, 0, 0);
            acc[g][t] = __builtin_amdgcn_mfma_f32_16x16x32_f16(a1l, b1, acc[g][t], 0, 0, 0);
        }
    }
    #undef LOADX

    // ---- routing (all fp32, per pixel), f = t*16 + q*4 + r ----
    // iter 0: v0[f] = 0.5*sum_g con ; beta1[g] = sum_f v0*con
    float v0[4][4];
    #pragma unroll
    for (int t = 0; t < 4; ++t)
        #pragma unroll
        for (int r = 0; r < 4; ++r) {
            float s = 0.f;
            #pragma unroll
            for (int g = 0; g < NG; ++g) s += acc[g][t][r];
            v0[t][r] = 0.5f * s;
        }

    float beta[NG], alpha[NG];
    #pragma unroll
    for (int g = 0; g < NG; ++g) {
        float s = 0.f;
        #pragma unroll
        for (int t = 0; t < 4; ++t)
            #pragma unroll
            for (int r = 0; r < 4; ++r)
                s += v0[t][r] * acc[g][t][r];
        s += __shfl_xor(s, 16);   // close f-sum across the 4 q-lanes
        s += __shfl_xor(s, 32);
        beta[g]  = s;
        alpha[g] = sigmoidf_fast(s);
    }

    // iter 1: v1[f] = sum_g alpha*con ; beta2 = beta1 + sum_f v1*con
    #pragma unroll
    for (int t = 0; t < 4; ++t)
        #pragma unroll
        for (int r = 0; r < 4; ++r) {
            float s = 0.f;
            #pragma unroll
            for (int g = 0; g < NG; ++g) s += alpha[g] * acc[g][t][r];
            v0[t][r] = s;  // reuse as v1
        }
    #pragma unroll
    for (int g = 0; g < NG; ++g) {
        float s = 0.f;
        #pragma unroll
        for (int t = 0; t < 4; ++t)
            #pragma unroll
            for (int r = 0; r < 4; ++r)
                s += v0[t][r] * acc[g][t][r];
        s += __shfl_xor(s, 16);
        s += __shfl_xor(s, 32);
        beta[g] += s;
        alpha[g] = sigmoidf_fast(beta[g]);
    }

    // iter 2: out[f] = sum_g alpha2*con + bias[f]
    #pragma unroll
    for (int t = 0; t < 4; ++t)
        #pragma unroll
        for (int r = 0; r < 4; ++r) {
            int f = t * 16 + q * 4 + r;
            float s = bias[f];
            #pragma unroll
            for (int g = 0; g < NG; ++g) s += alpha[g] * acc[g][t][r];
            out[((size_t)(b * NFO + f)) * HW + p0 + pw] = s;
        }
}

extern "C" void kernel_launch(void* const* d_in, const int* in_sizes, int n_in,
                              void* d_out, int out_size, void* d_ws, size_t ws_size,
                              hipStream_t stream) {
    const float* x    = (const float*)d_in[0];
    const float* w    = (const float*)d_in[1];
    const float* bias = (const float*)d_in[2];
    float* out = (float*)d_out;
    _Float16* wbuf = (_Float16*)d_ws;   // 128 KiB fragment-ordered (h,l) weights

    wconv_kernel<<<32, 256, 0, stream>>>(w, wbuf);
    routing_kernel<<<1024, 256, 0, stream>>>(x, wbuf, bias, out);
}

// Round 4
// 210.680 us; speedup vs baseline: 1.1736x; 1.0227x over previous
//
#include <hip/hip_runtime.h>

// DynamicRouting: grouped 1x1 conv (einsum bgihw,gfi->bgfhw) + 3-iter routing.
// B=16, G=8, FI=FO=64, HW=4096. Fully fused: con never touches HBM.
//
// R4: R3 structure (LDS-free, direct B-frag global loads, fragment-ordered
// split-fp16 weights) but the x prefetch pipeline is rebuilt with explicitly
// named scalar registers + depth-2 rotation (X0/X1/X2), fully macro-unrolled.
// R3's `float* cur = (g&1)? xv1:xv0` runtime pointer selection defeated SROA
// (VGPR_Count=84 with 128 acc regs => buffers went to scratch / loads were
// serialized). Numerics unchanged from R2/R3 (passed, absmax 0.125).

typedef __attribute__((ext_vector_type(8))) _Float16 half8;
typedef __attribute__((ext_vector_type(4))) float f32x4;

#define NG   8
#define NFI  64
#define NFO  64
#define HW   4096

__device__ __forceinline__ float sigmoidf_fast(float v) {
    float e = __builtin_amdgcn_exp2f(-1.44269504088896f * v);
    return __builtin_amdgcn_rcpf(1.0f + e);
}

// ---- kernel 1: repack weights fp32 -> fragment-ordered (h,l) fp16 ----
// wbuf[((g*4+t)*4+c)*512 + lane*8 + j]:
//   c=0: h, k=q*8+j   c=1: h, k=32+q*8+j   c=2: l, k=q*8+j   c=3: l, k=32+q*8+j
__global__ __launch_bounds__(256)
void wconv_kernel(const float* __restrict__ w, _Float16* __restrict__ wbuf) {
    int V = blockIdx.x * 256 + threadIdx.x;   // 0..8191 fragments
    int g    = V >> 10;
    int t    = (V >> 8) & 3;
    int c    = (V >> 6) & 3;
    int lane = V & 63;
    int pl = lane & 15, q = lane >> 4;
    const float* src = w + g * (NFO * NFI) + (t * 16 + pl) * NFI + (c & 1) * 32 + q * 8;
    half8 o;
    #pragma unroll
    for (int j = 0; j < 8; ++j) {
        float f = src[j];
        _Float16 h = (_Float16)f;
        o[j] = (c >> 1) ? (_Float16)(f - (float)h) : h;
    }
    *(half8*)(wbuf + (size_t)V * 8) = o;
}

// ---- kernel 2: fused conv + routing, LDS-free, depth-2 pipelined ----
__global__ __launch_bounds__(256, 2)
void routing_kernel(const float* __restrict__ x,
                    const _Float16* __restrict__ wbuf,
                    const float* __restrict__ bias,
                    float* __restrict__ out) {
    const int tid  = threadIdx.x;
    const int b    = blockIdx.x >> 6;          // batch
    const int p0   = (blockIdx.x & 63) << 6;   // pixel tile base
    const int lane = tid & 63;
    const int wv   = tid >> 6;                 // wave -> 16-px slice
    const int pl   = lane & 15;                // MFMA n-lane (pixel)
    const int q    = lane >> 4;                // k-octet select / C row group
    const int pw   = wv * 16 + pl;             // pixel within tile

    const float* xg = x + (size_t)b * (NG * NFI) * HW + p0 + pw;

    f32x4 acc[NG][4];
    #pragma unroll
    for (int g = 0; g < NG; ++g)
        #pragma unroll
        for (int t = 0; t < 4; ++t)
            acc[g][t] = (f32x4){0.f, 0.f, 0.f, 0.f};

    // explicitly named scalar buffers — no runtime-indexed private arrays
#define XDECL(NM) float NM##0, NM##1, NM##2, NM##3, NM##4, NM##5, NM##6, NM##7, \
                        NM##8, NM##9, NM##10, NM##11, NM##12, NM##13, NM##14, NM##15;
#define XLOAD(G, NM)                                                         \
    {                                                                        \
        const float* p_ = xg + (size_t)((G) * 64 + q * 8) * HW;              \
        NM##0 = p_[(size_t)0 * HW];  NM##1 = p_[(size_t)1 * HW];             \
        NM##2 = p_[(size_t)2 * HW];  NM##3 = p_[(size_t)3 * HW];             \
        NM##4 = p_[(size_t)4 * HW];  NM##5 = p_[(size_t)5 * HW];             \
        NM##6 = p_[(size_t)6 * HW];  NM##7 = p_[(size_t)7 * HW];             \
        const float* p2_ = p_ + (size_t)32 * HW;                             \
        NM##8  = p2_[(size_t)0 * HW]; NM##9  = p2_[(size_t)1 * HW];          \
        NM##10 = p2_[(size_t)2 * HW]; NM##11 = p2_[(size_t)3 * HW];          \
        NM##12 = p2_[(size_t)4 * HW]; NM##13 = p2_[(size_t)5 * HW];          \
        NM##14 = p2_[(size_t)6 * HW]; NM##15 = p2_[(size_t)7 * HW];          \
    }
#define XGRP(G, NM)                                                          \
    {                                                                        \
        half8 b0, b1;                                                        \
        b0[0] = (_Float16)NM##0;  b0[1] = (_Float16)NM##1;                   \
        b0[2] = (_Float16)NM##2;  b0[3] = (_Float16)NM##3;                   \
        b0[4] = (_Float16)NM##4;  b0[5] = (_Float16)NM##5;                   \
        b0[6] = (_Float16)NM##6;  b0[7] = (_Float16)NM##7;                   \
        b1[0] = (_Float16)NM##8;  b1[1] = (_Float16)NM##9;                   \
        b1[2] = (_Float16)NM##10; b1[3] = (_Float16)NM##11;                  \
        b1[4] = (_Float16)NM##12; b1[5] = (_Float16)NM##13;                  \
        b1[6] = (_Float16)NM##14; b1[7] = (_Float16)NM##15;                  \
        const _Float16* wg_ = wbuf + (size_t)(G) * 16 * 512 + lane * 8;      \
        _Pragma("unroll")                                                    \
        for (int t = 0; t < 4; ++t) {                                        \
            const _Float16* wp_ = wg_ + (size_t)t * 2048;                    \
            half8 a0h = *(const half8*)(wp_);                                \
            half8 a1h = *(const half8*)(wp_ + 512);                          \
            half8 a0l = *(const half8*)(wp_ + 1024);                         \
            half8 a1l = *(const half8*)(wp_ + 1536);                         \
            acc[G][t] = __builtin_amdgcn_mfma_f32_16x16x32_f16(a0h, b0, acc[G][t], 0, 0, 0); \
            acc[G][t] = __builtin_amdgcn_mfma_f32_16x16x32_f16(a1h, b1, acc[G][t], 0, 0, 0); \
            acc[G][t] = __builtin_amdgcn_mfma_f32_16x16x32_f16(a0l, b0, acc[G][t], 0, 0, 0); \
            acc[G][t] = __builtin_amdgcn_mfma_f32_16x16x32_f16(a1l, b1, acc[G][t], 0, 0, 0); \
        }                                                                    \
    }

    XDECL(X0) XDECL(X1) XDECL(X2)

    XLOAD(0, X0)
    XLOAD(1, X1)
    XLOAD(2, X2) XGRP(0, X0)
    XLOAD(3, X0) XGRP(1, X1)
    XLOAD(4, X1) XGRP(2, X2)
    XLOAD(5, X2) XGRP(3, X0)
    XLOAD(6, X0) XGRP(4, X1)
    XLOAD(7, X1) XGRP(5, X2)
    XGRP(6, X0)
    XGRP(7, X1)

#undef XDECL
#undef XLOAD
#undef XGRP

    // ---- routing (all fp32, per pixel), f = t*16 + q*4 + r ----
    // iter 0: v0[f] = 0.5*sum_g con ; beta1[g] = sum_f v0*con
    float v0[4][4];
    #pragma unroll
    for (int t = 0; t < 4; ++t)
        #pragma unroll
        for (int r = 0; r < 4; ++r) {
            float s = 0.f;
            #pragma unroll
            for (int g = 0; g < NG; ++g) s += acc[g][t][r];
            v0[t][r] = 0.5f * s;
        }

    float beta[NG], alpha[NG];
    #pragma unroll
    for (int g = 0; g < NG; ++g) {
        float s = 0.f;
        #pragma unroll
        for (int t = 0; t < 4; ++t)
            #pragma unroll
            for (int r = 0; r < 4; ++r)
                s += v0[t][r] * acc[g][t][r];
        s += __shfl_xor(s, 16);   // close f-sum across the 4 q-lanes
        s += __shfl_xor(s, 32);
        beta[g]  = s;
        alpha[g] = sigmoidf_fast(s);
    }

    // iter 1: v1[f] = sum_g alpha*con ; beta2 = beta1 + sum_f v1*con
    #pragma unroll
    for (int t = 0; t < 4; ++t)
        #pragma unroll
        for (int r = 0; r < 4; ++r) {
            float s = 0.f;
            #pragma unroll
            for (int g = 0; g < NG; ++g) s += alpha[g] * acc[g][t][r];
            v0[t][r] = s;  // reuse as v1
        }
    #pragma unroll
    for (int g = 0; g < NG; ++g) {
        float s = 0.f;
        #pragma unroll
        for (int t = 0; t < 4; ++t)
            #pragma unroll
            for (int r = 0; r < 4; ++r)
                s += v0[t][r] * acc[g][t][r];
        s += __shfl_xor(s, 16);
        s += __shfl_xor(s, 32);
        beta[g] += s;
        alpha[g] = sigmoidf_fast(beta[g]);
    }

    // iter 2: out[f] = sum_g alpha2*con + bias[f]
    #pragma unroll
    for (int t = 0; t < 4; ++t)
        #pragma unroll
        for (int r = 0; r < 4; ++r) {
            int f = t * 16 + q * 4 + r;
            float s = bias[f];
            #pragma unroll
            for (int g = 0; g < NG; ++g) s += alpha[g] * acc[g][t][r];
            out[((size_t)(b * NFO + f)) * HW + p0 + pw] = s;
        }
}

extern "C" void kernel_launch(void* const* d_in, const int* in_sizes, int n_in,
                              void* d_out, int out_size, void* d_ws, size_t ws_size,
                              hipStream_t stream) {
    const float* x    = (const float*)d_in[0];
    const float* w    = (const float*)d_in[1];
    const float* bias = (const float*)d_in[2];
    float* out = (float*)d_out;
    _Float16* wbuf = (_Float16*)d_ws;   // 128 KiB fragment-ordered (h,l) weights

    wconv_kernel<<<32, 256, 0, stream>>>(w, wbuf);
    routing_kernel<<<1024, 256, 0, stream>>>(x, wbuf, bias, out);
}